// Round 16
// baseline (38.123 us; speedup 1.0000x reference)
//
#include <hip/hip_runtime.h>
#include <math.h>

// Bahdanau attention, fp32. B=4, TQ=TV=256, H=D=512, U=256.
// out = [context (4*256*512)] ++ [attn (4*256*256)]
//
// tanh(x) = 1 - 2/(e^{2x}+1); e^{2(q+v)} = e^{2q}*e^{2v}.
// Ledger: C~21.5 fixed | proj ~4.5 | score 0.9 | ctx ~5 | gaps.
// R16: ctx rebuilt on the R15-proven single-stage full-K pattern (one load
// burst -> one barrier -> pure-LDS MFMA loop). A = attn rows f32 direct,
// B = values cols f32 coalesced gather, reg-convert to bf16. valT transpose
// job and attnbf store are now dead - deleted (fewer bytes, fewer deps).

typedef float f4 __attribute__((ext_vector_type(4)));
typedef float f2 __attribute__((ext_vector_type(2)));
typedef __attribute__((ext_vector_type(8))) short s8v;            // 8 bf16
typedef __attribute__((ext_vector_type(8))) unsigned short u8v;   // 8 bf16

#define B_    4
#define TQ_   256
#define TV_   256
#define D_    512
#define U_    256
#define KDIM  512          // H == D == 512
#define MROWS 1024         // B*TQ == B*TV

#define C2LOG2E 2.8853900817779268f   // 2*log2(e)

// ws layout: Eq f32 [1024][256] @ 0 (1MB) | EvT bf16 [256 u][1024 vg] @ 1MB
#define EVT_U16_OFF   524288

#if __has_builtin(__builtin_amdgcn_exp2f)
#define EXP2F(x) __builtin_amdgcn_exp2f(x)
#else
#define EXP2F(x) exp2f(x)
#endif
#if __has_builtin(__builtin_amdgcn_rcpf)
#define RCPF(x) __builtin_amdgcn_rcpf(x)
#else
#define RCPF(x) (1.0f / (x))
#endif

__device__ __forceinline__ unsigned short f2bf(float f) {   // RNE f32->bf16
    union { float f; unsigned u; } v; v.f = f;
    return (unsigned short)((v.u + 0x7FFF + ((v.u >> 16) & 1)) >> 16);
}
__device__ __forceinline__ float bf2f(unsigned short h) {
    union { unsigned u; float f; } v; v.u = (unsigned)h << 16;
    return v.f;
}
__device__ __forceinline__ u8v pack8(const f4 a, const f4 b) {
    u8v o;
    o[0] = f2bf(a[0]); o[1] = f2bf(a[1]); o[2] = f2bf(a[2]); o[3] = f2bf(a[3]);
    o[4] = f2bf(b[0]); o[5] = f2bf(b[1]); o[6] = f2bf(b[2]); o[7] = f2bf(b[3]);
    return o;
}

// ---------------- proj GEMMs, single-stage full-K LDS (R15) ----------------
// blockIdx.y: 0 -> Eq (f32), 1 -> EvT (bf16).
// 32x32 tile, K=512 entirely in LDS (64KB), XOR-swizzled 16B units.
__global__ __launch_bounds__(256) void proj_mfma(
    const float* __restrict__ query, const float* __restrict__ values,
    const float* __restrict__ W1, const float* __restrict__ b1,
    const float* __restrict__ W2, const float* __restrict__ b2,
    float* __restrict__ ws)
{
    const int tid = threadIdx.x;

    __shared__ u8v Al[32][64];
    __shared__ u8v Bl[32][64];

    const int proj = blockIdx.y;
    const int x    = blockIdx.x;

    int m0, n0;
    if (proj == 0) { m0 = (x >> 3) * 32; n0 = (x & 7) * 32; }   // 32 x 8
    else           { m0 = (x & 7) * 32;  n0 = (x >> 3) * 32; }  // 8 x 32

    // direct path: row = tid>>3 (0..31), 64 consecutive k @ unit base duc
    const int drow = tid >> 3;
    const int duc  = (tid & 7) * 8;   // 16B-unit base (8 units = 64 elems)
    const float* dsrc = (proj ? values + (size_t)(n0 + drow) * KDIM
                              : query  + (size_t)(m0 + drow) * KDIM) + duc * 8;

    // gather path: col = tid&31 (lane-consecutive -> coalesced), 64 k's
    const int gcol = tid & 31;
    const int gk0  = (tid >> 5) * 64;
    const float* gsrc = (proj ? W2 + (m0 + gcol) : W1 + (n0 + gcol))
                        + (size_t)gk0 * U_;

    u8v (*DIR)[64] = proj ? Bl : Al;   // proj0: A=query rows, B=W1 cols
    u8v (*GAT)[64] = proj ? Al : Bl;   // proj1: B=values rows, A=W2 cols

    // ---- one load burst: 16 f4 + 64 dwords in flight per thread
    f4 dv[16];
    #pragma unroll
    for (int j = 0; j < 16; ++j) dv[j] = *(const f4*)(dsrc + j * 4);
    float gv[64];
    #pragma unroll
    for (int j = 0; j < 64; ++j) gv[j] = gsrc[(size_t)j * U_];

    // ---- pack bf16 + swizzled LDS writes
    #pragma unroll
    for (int j = 0; j < 8; ++j)
        DIR[drow][(duc + j) ^ (drow & 7)] = pack8(dv[2 * j], dv[2 * j + 1]);
    #pragma unroll
    for (int g = 0; g < 8; ++g) {
        u8v o;
        #pragma unroll
        for (int j = 0; j < 8; ++j) o[j] = f2bf(gv[g * 8 + j]);
        GAT[gcol][((gk0 >> 3) + g) ^ (gcol & 7)] = o;
    }
    __syncthreads();

    // ---- K-loop: pure LDS + MFMA, no barriers
    f4 acc = {};
    const int w    = tid >> 6;
    const int l    = tid & 63;
    const int fr   = l & 15;
    const int fko  = l >> 4;          // 16B-unit offset within 32-k step
    const int band = (w & 1) * 16;
    const int colh = (w >> 1) * 16;
    const int ar   = band + fr;
    const int br   = colh + fr;

    #pragma unroll
    for (int s = 0; s < 16; ++s) {
        s8v af = *(const s8v*)&Al[ar][(fko + 4 * s) ^ (ar & 7)];
        s8v bf = *(const s8v*)&Bl[br][(fko + 4 * s) ^ (br & 7)];
        acc = __builtin_amdgcn_mfma_f32_16x16x32_bf16(af, bf, acc, 0, 0, 0);
    }

    // ---- epilogue (C/D: col=l&15, row=(l>>4)*4+r)
    const int orow = m0 + band + (l >> 4) * 4;
    const int ocol = n0 + colh + (l & 15);

    if (proj == 0) {
        float* E = ws;                // Eq[1024][256] fp32
        const float bias = b1[ocol];
        #pragma unroll
        for (int r = 0; r < 4; ++r)
            E[(size_t)(orow + r) * U_ + ocol] =
                EXP2F((acc[r] + bias) * C2LOG2E);
    } else {
        unsigned short* E = (unsigned short*)ws + EVT_U16_OFF;  // EvT bf16
        #pragma unroll
        for (int r = 0; r < 4; ++r)
            E[(size_t)(orow + r) * MROWS + ocol] =
                f2bf(EXP2F((acc[r] + b2[orow + r]) * C2LOG2E));
    }
}

// ---------------- score + softmax (attn -> out f32 only) ----------------
__global__ __launch_bounds__(256) void score_softmax(
    const float* __restrict__ Vw, float* __restrict__ ws,
    float* __restrict__ out)
{
    __shared__ float redmin[4][2];
    __shared__ float redsum[4][2];

    const int tid = threadIdx.x;
    const int b  = blockIdx.y;
    const int q0 = blockIdx.x * 2;

    const float* eq0 = ws + (size_t)(b * TQ_ + q0) * U_;            // uniform
    const float* eq1 = eq0 + U_;                                    // uniform
    const unsigned short* evp =
        (const unsigned short*)ws + EVT_U16_OFF + (size_t)b * TV_ + tid;
    float* attn = out + (size_t)B_ * TQ_ * D_ + (size_t)(b * TQ_ + q0) * TV_;

    float evA[8], evB[8];
    #pragma unroll
    for (int i = 0; i < 8; ++i) evA[i] = bf2f(evp[(size_t)i * MROWS]);

    f2 p = {0.f, 0.f};
    const f2 one = {1.0f, 1.0f};

#define SGRP(BUF, G)                                                    \
    _Pragma("unroll")                                                   \
    for (int i = 0; i < 8; ++i) {                                       \
        const int u = (G) * 8 + i;                                      \
        f2 eq = {eq0[u], eq1[u]};      /* s_load pair */                \
        f2 ev2 = {BUF[i], BUF[i]};                                      \
        f2 den = eq * ev2 + one;       /* v_pk_fma_f32 */               \
        f2 r = {RCPF(den.x), RCPF(den.y)};                              \
        f2 wv = {Vw[u], Vw[u]};        /* s_load */                     \
        p = wv * r + p;                /* v_pk_fma_f32 */               \
    }

    #pragma unroll
    for (int g = 0; g < 32; g += 2) {
        #pragma unroll
        for (int i = 0; i < 8; ++i)
            evB[i] = bf2f(evp[(size_t)((g + 1) * 8 + i) * MROWS]);
        SGRP(evA, g)
        if (g + 2 < 32) {
            #pragma unroll
            for (int i = 0; i < 8; ++i)
                evA[i] = bf2f(evp[(size_t)((g + 2) * 8 + i) * MROWS]);
        }
        SGRP(evB, g + 1)
    }
#undef SGRP

    // softmax over v (score = const - 2p: max score = min p)
    const int w = tid >> 6, lane = tid & 63;
    float m0 = p.x, m1 = p.y;
    #pragma unroll
    for (int off = 32; off; off >>= 1) {
        m0 = fminf(m0, __shfl_xor(m0, off));
        m1 = fminf(m1, __shfl_xor(m1, off));
    }
    if (lane == 0) { redmin[w][0] = m0; redmin[w][1] = m1; }
    __syncthreads();
    m0 = fminf(fminf(redmin[0][0], redmin[1][0]),
               fminf(redmin[2][0], redmin[3][0]));
    m1 = fminf(fminf(redmin[0][1], redmin[1][1]),
               fminf(redmin[2][1], redmin[3][1]));

    float e0 = EXP2F((m0 - p.x) * C2LOG2E);
    float e1 = EXP2F((m1 - p.y) * C2LOG2E);

    float s0 = e0, s1 = e1;
    #pragma unroll
    for (int off = 32; off; off >>= 1) {
        s0 += __shfl_xor(s0, off);
        s1 += __shfl_xor(s1, off);
    }
    if (lane == 0) { redsum[w][0] = s0; redsum[w][1] = s1; }
    __syncthreads();
    s0 = redsum[0][0] + redsum[1][0] + redsum[2][0] + redsum[3][0];
    s1 = redsum[0][1] + redsum[1][1] + redsum[2][1] + redsum[3][1];

    attn[tid]       = e0 * (1.0f / s0);   // exact division
    attn[TV_ + tid] = e1 * (1.0f / s1);
}

// ---------------- context = attn @ values, single-stage full-K ----------
// C[q][d] = sum_v attn[q][v] * values[v][d]. 32x32 tile, K=256 entirely in
// LDS (32KB). A = attn rows f32 (8xf4 burst), B = values cols f32 (32
// coalesced strided dwords), reg-convert bf16, XOR-swizzled writes, ONE
// barrier, 8 MFMA steps pure-LDS. blockIdx.x: m=x>>4 (8), n=x&15 (16).
__global__ __launch_bounds__(256) void ctx_mfma(
    const float* __restrict__ values, float* __restrict__ out)
{
    __shared__ u8v Al[32][32];
    __shared__ u8v Bl[32][32];

    const int tid = threadIdx.x;
    const int b   = blockIdx.y;
    const int x   = blockIdx.x;
    const int m0  = (x >> 4) * 32;    // q-tile (8)
    const int n0  = (x & 15) * 32;    // d-tile (16)

    const float* attn = out + (size_t)B_ * TQ_ * D_ + (size_t)b * TQ_ * TV_;
    const float* valb = values + (size_t)b * TV_ * D_;

    // A direct: row = tid>>3 (0..31), 32 consecutive v @ unit base duc
    const int drow = tid >> 3;
    const int duc  = (tid & 7) * 4;   // 4 units = 32 elems
    const float* asrc = attn + (size_t)(m0 + drow) * TV_ + duc * 8;

    // B gather: col = tid&31 (lane-consecutive d -> coalesced), 32 k's
    const int gcol = tid & 31;
    const int gk0  = (tid >> 5) * 32;
    const float* bsrc = valb + (size_t)gk0 * D_ + n0 + gcol;

    // ---- one load burst: 8 f4 + 32 dwords per thread
    f4 av[8];
    #pragma unroll
    for (int j = 0; j < 8; ++j) av[j] = *(const f4*)(asrc + j * 4);
    float bv[32];
    #pragma unroll
    for (int j = 0; j < 32; ++j) bv[j] = bsrc[(size_t)j * D_];

    // ---- pack bf16 + swizzled LDS writes
    #pragma unroll
    for (int j = 0; j < 4; ++j)
        Al[drow][(duc + j) ^ (drow & 7)] = pack8(av[2 * j], av[2 * j + 1]);
    #pragma unroll
    for (int g = 0; g < 4; ++g) {
        u8v o;
        #pragma unroll
        for (int j = 0; j < 8; ++j) o[j] = f2bf(bv[g * 8 + j]);
        Bl[gcol][((gk0 >> 3) + g) ^ (gcol & 7)] = o;
    }
    __syncthreads();

    // ---- K-loop: 8 steps, pure LDS + MFMA
    f4 acc = {};
    const int w    = tid >> 6;
    const int l    = tid & 63;
    const int fr   = l & 15;
    const int fko  = l >> 4;
    const int band = (w & 1) * 16;
    const int colh = (w >> 1) * 16;
    const int ar   = band + fr;
    const int br   = colh + fr;

    #pragma unroll
    for (int s = 0; s < 8; ++s) {
        s8v af = *(const s8v*)&Al[ar][(fko + 4 * s) ^ (ar & 7)];
        s8v bf = *(const s8v*)&Bl[br][(fko + 4 * s) ^ (br & 7)];
        acc = __builtin_amdgcn_mfma_f32_16x16x32_bf16(af, bf, acc, 0, 0, 0);
    }

    const int orow = m0 + band + (l >> 4) * 4;
    const int ocol = n0 + colh + (l & 15);
    float* C = out + (size_t)b * TQ_ * D_;

    #pragma unroll
    for (int r = 0; r < 4; ++r)
        C[(size_t)(orow + r) * D_ + ocol] = acc[r];
}

extern "C" void kernel_launch(void* const* d_in, const int* in_sizes, int n_in,
                              void* d_out, int out_size, void* d_ws, size_t ws_size,
                              hipStream_t stream) {
    const float* query  = (const float*)d_in[0];
    const float* values = (const float*)d_in[1];
    const float* W1     = (const float*)d_in[2];
    const float* b1     = (const float*)d_in[3];
    const float* W2     = (const float*)d_in[4];
    const float* b2     = (const float*)d_in[5];
    const float* Vw     = (const float*)d_in[6];
    float* out = (float*)d_out;
    float* ws  = (float*)d_ws;

    proj_mfma<<<dim3(256, 2), 256, 0, stream>>>(query, values, W1, b1, W2, b2, ws);
    score_softmax<<<dim3(TQ_ / 2, B_), 256, 0, stream>>>(Vw, ws, out);
    ctx_mfma<<<dim3(128, B_), 256, 0, stream>>>(values, out);
}

// Round 17
// 34.956 us; speedup vs baseline: 1.0906x; 1.0906x over previous
//
#include <hip/hip_runtime.h>
#include <math.h>

// Bahdanau attention, fp32. B=4, TQ=TV=256, H=D=512, U=256.
// out = [context (4*256*512)] ++ [attn (4*256*256)]
//
// tanh(x) = 1 - 2/(e^{2x}+1); e^{2(q+v)} = e^{2q}*e^{2v}.
// R17 = R15 + ctx hybrid: single-stage full-K (R15-proven) FROM bf16
// sources (R14-proven). R16's ablation showed f32-source staging (40 cvt +
// 32 strided gathers) cost more than the dbuf it replaced; this keeps the
// one-burst/one-barrier shape but stages 8 contiguous u8v copies instead.
// valT transpose + attnbf store restored (measured ~0.8us combined).

typedef float f4 __attribute__((ext_vector_type(4)));
typedef float f2 __attribute__((ext_vector_type(2)));
typedef __attribute__((ext_vector_type(8))) short s8v;            // 8 bf16
typedef __attribute__((ext_vector_type(8))) unsigned short u8v;   // 8 bf16

#define B_    4
#define TQ_   256
#define TV_   256
#define D_    512
#define U_    256
#define KDIM  512          // H == D == 512
#define MROWS 1024         // B*TQ == B*TV

#define C2LOG2E 2.8853900817779268f   // 2*log2(e)

// ws layout (u16 elems): Eq f32 [1024][256] @ 0 | EvT bf16 @ 524288
//                        attnbf bf16 @ 786432 | valT bf16 @ 1048576
#define EVT_U16_OFF   524288
#define ATTN_U16_OFF  786432
#define VALT_U16_OFF 1048576

#if __has_builtin(__builtin_amdgcn_exp2f)
#define EXP2F(x) __builtin_amdgcn_exp2f(x)
#else
#define EXP2F(x) exp2f(x)
#endif
#if __has_builtin(__builtin_amdgcn_rcpf)
#define RCPF(x) __builtin_amdgcn_rcpf(x)
#else
#define RCPF(x) (1.0f / (x))
#endif

__device__ __forceinline__ unsigned short f2bf(float f) {   // RNE f32->bf16
    union { float f; unsigned u; } v; v.f = f;
    return (unsigned short)((v.u + 0x7FFF + ((v.u >> 16) & 1)) >> 16);
}
__device__ __forceinline__ float bf2f(unsigned short h) {
    union { unsigned u; float f; } v; v.u = (unsigned)h << 16;
    return v.f;
}
__device__ __forceinline__ u8v pack8(const f4 a, const f4 b) {
    u8v o;
    o[0] = f2bf(a[0]); o[1] = f2bf(a[1]); o[2] = f2bf(a[2]); o[3] = f2bf(a[3]);
    o[4] = f2bf(b[0]); o[5] = f2bf(b[1]); o[6] = f2bf(b[2]); o[7] = f2bf(b[3]);
    return o;
}

// ---------------- proj GEMMs, single-stage full-K LDS (R15) ----------------
// blockIdx.y: 0 -> Eq (f32), 1 -> EvT (bf16), 2 -> valT transpose.
__global__ __launch_bounds__(256) void proj_mfma(
    const float* __restrict__ query, const float* __restrict__ values,
    const float* __restrict__ W1, const float* __restrict__ b1,
    const float* __restrict__ W2, const float* __restrict__ b2,
    float* __restrict__ ws)
{
    const int tid = threadIdx.x;
    const int job = blockIdx.y;

    if (job == 2) {
        // valT[b][d][v] = bf16(values[b][v][d]). Coalesced reads, u8v writes.
        const int idx = blockIdx.x * 256 + tid;   // 0..65535
        const int d   = idx & 511;
        const int vg  = (idx >> 9) & 31;          // v-group of 8
        const int b   = idx >> 14;
        const float* src = values + ((size_t)b * TV_ + vg * 8) * KDIM + d;
        unsigned short* valT = (unsigned short*)ws + VALT_U16_OFF;
        u8v o;
        #pragma unroll
        for (int j = 0; j < 8; ++j) o[j] = f2bf(src[(size_t)j * KDIM]);
        *(u8v*)(valT + ((size_t)b * D_ + d) * TV_ + vg * 8) = o;
        return;
    }

    __shared__ u8v Al[32][64];
    __shared__ u8v Bl[32][64];

    const int proj = job;
    const int x    = blockIdx.x;

    int m0, n0;
    if (proj == 0) { m0 = (x >> 3) * 32; n0 = (x & 7) * 32; }   // 32 x 8
    else           { m0 = (x & 7) * 32;  n0 = (x >> 3) * 32; }  // 8 x 32

    // direct path: row = tid>>3 (0..31), 64 consecutive k @ unit base duc
    const int drow = tid >> 3;
    const int duc  = (tid & 7) * 8;   // 16B-unit base (8 units = 64 elems)
    const float* dsrc = (proj ? values + (size_t)(n0 + drow) * KDIM
                              : query  + (size_t)(m0 + drow) * KDIM) + duc * 8;

    // gather path: col = tid&31 (lane-consecutive -> coalesced), 64 k's
    const int gcol = tid & 31;
    const int gk0  = (tid >> 5) * 64;
    const float* gsrc = (proj ? W2 + (m0 + gcol) : W1 + (n0 + gcol))
                        + (size_t)gk0 * U_;

    u8v (*DIR)[64] = proj ? Bl : Al;   // proj0: A=query rows, B=W1 cols
    u8v (*GAT)[64] = proj ? Al : Bl;   // proj1: B=values rows, A=W2 cols

    // ---- one load burst: 16 f4 + 64 dwords in flight per thread
    f4 dv[16];
    #pragma unroll
    for (int j = 0; j < 16; ++j) dv[j] = *(const f4*)(dsrc + j * 4);
    float gv[64];
    #pragma unroll
    for (int j = 0; j < 64; ++j) gv[j] = gsrc[(size_t)j * U_];

    // ---- pack bf16 + swizzled LDS writes
    #pragma unroll
    for (int j = 0; j < 8; ++j)
        DIR[drow][(duc + j) ^ (drow & 7)] = pack8(dv[2 * j], dv[2 * j + 1]);
    #pragma unroll
    for (int g = 0; g < 8; ++g) {
        u8v o;
        #pragma unroll
        for (int j = 0; j < 8; ++j) o[j] = f2bf(gv[g * 8 + j]);
        GAT[gcol][((gk0 >> 3) + g) ^ (gcol & 7)] = o;
    }
    __syncthreads();

    // ---- K-loop: pure LDS + MFMA, no barriers
    f4 acc = {};
    const int w    = tid >> 6;
    const int l    = tid & 63;
    const int fr   = l & 15;
    const int fko  = l >> 4;          // 16B-unit offset within 32-k step
    const int band = (w & 1) * 16;
    const int colh = (w >> 1) * 16;
    const int ar   = band + fr;
    const int br   = colh + fr;

    #pragma unroll
    for (int s = 0; s < 16; ++s) {
        s8v af = *(const s8v*)&Al[ar][(fko + 4 * s) ^ (ar & 7)];
        s8v bf = *(const s8v*)&Bl[br][(fko + 4 * s) ^ (br & 7)];
        acc = __builtin_amdgcn_mfma_f32_16x16x32_bf16(af, bf, acc, 0, 0, 0);
    }

    // ---- epilogue (C/D: col=l&15, row=(l>>4)*4+r)
    const int orow = m0 + band + (l >> 4) * 4;
    const int ocol = n0 + colh + (l & 15);

    if (proj == 0) {
        float* E = ws;                // Eq[1024][256] fp32
        const float bias = b1[ocol];
        #pragma unroll
        for (int r = 0; r < 4; ++r)
            E[(size_t)(orow + r) * U_ + ocol] =
                EXP2F((acc[r] + bias) * C2LOG2E);
    } else {
        unsigned short* E = (unsigned short*)ws + EVT_U16_OFF;  // EvT bf16
        #pragma unroll
        for (int r = 0; r < 4; ++r)
            E[(size_t)(orow + r) * MROWS + ocol] =
                f2bf(EXP2F((acc[r] + b2[orow + r]) * C2LOG2E));
    }
}

// ---------------- score + softmax (attn -> out f32 + ws bf16) ----------------
__global__ __launch_bounds__(256) void score_softmax(
    const float* __restrict__ Vw, float* __restrict__ ws,
    float* __restrict__ out)
{
    __shared__ float redmin[4][2];
    __shared__ float redsum[4][2];

    const int tid = threadIdx.x;
    const int b  = blockIdx.y;
    const int q0 = blockIdx.x * 2;

    const float* eq0 = ws + (size_t)(b * TQ_ + q0) * U_;            // uniform
    const float* eq1 = eq0 + U_;                                    // uniform
    const unsigned short* evp =
        (const unsigned short*)ws + EVT_U16_OFF + (size_t)b * TV_ + tid;
    float* attn = out + (size_t)B_ * TQ_ * D_ + (size_t)(b * TQ_ + q0) * TV_;
    unsigned short* attnbf =
        (unsigned short*)ws + ATTN_U16_OFF + (size_t)(b * TQ_ + q0) * TV_;

    float evA[8], evB[8];
    #pragma unroll
    for (int i = 0; i < 8; ++i) evA[i] = bf2f(evp[(size_t)i * MROWS]);

    f2 p = {0.f, 0.f};
    const f2 one = {1.0f, 1.0f};

#define SGRP(BUF, G)                                                    \
    _Pragma("unroll")                                                   \
    for (int i = 0; i < 8; ++i) {                                       \
        const int u = (G) * 8 + i;                                      \
        f2 eq = {eq0[u], eq1[u]};      /* s_load pair */                \
        f2 ev2 = {BUF[i], BUF[i]};                                      \
        f2 den = eq * ev2 + one;       /* v_pk_fma_f32 */               \
        f2 r = {RCPF(den.x), RCPF(den.y)};                              \
        f2 wv = {Vw[u], Vw[u]};        /* s_load */                     \
        p = wv * r + p;                /* v_pk_fma_f32 */               \
    }

    #pragma unroll
    for (int g = 0; g < 32; g += 2) {
        #pragma unroll
        for (int i = 0; i < 8; ++i)
            evB[i] = bf2f(evp[(size_t)((g + 1) * 8 + i) * MROWS]);
        SGRP(evA, g)
        if (g + 2 < 32) {
            #pragma unroll
            for (int i = 0; i < 8; ++i)
                evA[i] = bf2f(evp[(size_t)((g + 2) * 8 + i) * MROWS]);
        }
        SGRP(evB, g + 1)
    }
#undef SGRP

    // softmax over v (score = const - 2p: max score = min p)
    const int w = tid >> 6, lane = tid & 63;
    float m0 = p.x, m1 = p.y;
    #pragma unroll
    for (int off = 32; off; off >>= 1) {
        m0 = fminf(m0, __shfl_xor(m0, off));
        m1 = fminf(m1, __shfl_xor(m1, off));
    }
    if (lane == 0) { redmin[w][0] = m0; redmin[w][1] = m1; }
    __syncthreads();
    m0 = fminf(fminf(redmin[0][0], redmin[1][0]),
               fminf(redmin[2][0], redmin[3][0]));
    m1 = fminf(fminf(redmin[0][1], redmin[1][1]),
               fminf(redmin[2][1], redmin[3][1]));

    float e0 = EXP2F((m0 - p.x) * C2LOG2E);
    float e1 = EXP2F((m1 - p.y) * C2LOG2E);

    float s0 = e0, s1 = e1;
    #pragma unroll
    for (int off = 32; off; off >>= 1) {
        s0 += __shfl_xor(s0, off);
        s1 += __shfl_xor(s1, off);
    }
    if (lane == 0) { redsum[w][0] = s0; redsum[w][1] = s1; }
    __syncthreads();
    s0 = redsum[0][0] + redsum[1][0] + redsum[2][0] + redsum[3][0];
    s1 = redsum[0][1] + redsum[1][1] + redsum[2][1] + redsum[3][1];

    const float a0 = e0 * (1.0f / s0);    // exact division
    const float a1 = e1 * (1.0f / s1);
    attn[tid]         = a0;
    attn[TV_ + tid]   = a1;
    attnbf[tid]       = f2bf(a0);
    attnbf[TV_ + tid] = f2bf(a1);
}

// ---------------- context: single-stage full-K from bf16 sources ----------
// C[q][d] = sum_v attn[q][v] * valT[d][v]. 32x32 tile, K=256 in LDS (32KB).
// Staging = 8 contiguous u8v loads/thread (one burst, zero cvt), swizzled
// LDS copy, ONE barrier, 8 MFMA steps pure-LDS. m=x>>4 (8), n=x&15 (16).
__global__ __launch_bounds__(256) void ctx_mfma(
    const float* __restrict__ ws_ro, float* __restrict__ out)
{
    __shared__ u8v Al[32][32];
    __shared__ u8v Bl[32][32];

    const int tid = threadIdx.x;
    const int b   = blockIdx.y;
    const int x   = blockIdx.x;
    const int m0  = (x >> 4) * 32;    // q-tile (8)
    const int n0  = (x & 15) * 32;    // d-tile (16)

    const unsigned short* attnbf =
        (const unsigned short*)ws_ro + ATTN_U16_OFF;
    const unsigned short* valT =
        (const unsigned short*)ws_ro + VALT_U16_OFF;

    const int row = tid >> 3;         // 0..31
    const int uc0 = (tid & 7) * 4;    // 16B-unit base (4 units = 32 elems)

    const unsigned short* asrc =
        attnbf + ((size_t)(b * TQ_ + m0 + row)) * TV_ + uc0 * 8;
    const unsigned short* bsrc =
        valT + ((size_t)(b * D_ + n0 + row)) * TV_ + uc0 * 8;

    // ---- one load burst: 8 contiguous u8v per thread
    u8v a0 = *(const u8v*)(asrc);
    u8v a1 = *(const u8v*)(asrc + 8);
    u8v a2 = *(const u8v*)(asrc + 16);
    u8v a3 = *(const u8v*)(asrc + 24);
    u8v v0 = *(const u8v*)(bsrc);
    u8v v1 = *(const u8v*)(bsrc + 8);
    u8v v2 = *(const u8v*)(bsrc + 16);
    u8v v3 = *(const u8v*)(bsrc + 24);

    // ---- swizzled LDS copy
    const int sw = row & 7;
    Al[row][(uc0 + 0) ^ sw] = a0;
    Al[row][(uc0 + 1) ^ sw] = a1;
    Al[row][(uc0 + 2) ^ sw] = a2;
    Al[row][(uc0 + 3) ^ sw] = a3;
    Bl[row][(uc0 + 0) ^ sw] = v0;
    Bl[row][(uc0 + 1) ^ sw] = v1;
    Bl[row][(uc0 + 2) ^ sw] = v2;
    Bl[row][(uc0 + 3) ^ sw] = v3;
    __syncthreads();

    // ---- K-loop: 8 steps, pure LDS + MFMA
    f4 acc = {};
    const int w    = tid >> 6;
    const int l    = tid & 63;
    const int fr   = l & 15;
    const int fko  = l >> 4;
    const int band = (w & 1) * 16;
    const int colh = (w >> 1) * 16;
    const int ar   = band + fr;
    const int br   = colh + fr;

    #pragma unroll
    for (int s = 0; s < 8; ++s) {
        s8v af = *(const s8v*)&Al[ar][(fko + 4 * s) ^ (ar & 7)];
        s8v bf = *(const s8v*)&Bl[br][(fko + 4 * s) ^ (br & 7)];
        acc = __builtin_amdgcn_mfma_f32_16x16x32_bf16(af, bf, acc, 0, 0, 0);
    }

    const int orow = m0 + band + (l >> 4) * 4;
    const int ocol = n0 + colh + (l & 15);
    float* C = out + (size_t)b * TQ_ * D_;

    #pragma unroll
    for (int r = 0; r < 4; ++r)
        C[(size_t)(orow + r) * D_ + ocol] = acc[r];
}

extern "C" void kernel_launch(void* const* d_in, const int* in_sizes, int n_in,
                              void* d_out, int out_size, void* d_ws, size_t ws_size,
                              hipStream_t stream) {
    const float* query  = (const float*)d_in[0];
    const float* values = (const float*)d_in[1];
    const float* W1     = (const float*)d_in[2];
    const float* b1     = (const float*)d_in[3];
    const float* W2     = (const float*)d_in[4];
    const float* b2     = (const float*)d_in[5];
    const float* Vw     = (const float*)d_in[6];
    float* out = (float*)d_out;
    float* ws  = (float*)d_ws;

    proj_mfma<<<dim3(256, 3), 256, 0, stream>>>(query, values, W1, b1, W2, b2, ws);
    score_softmax<<<dim3(TQ_ / 2, B_), 256, 0, stream>>>(Vw, ws, out);
    ctx_mfma<<<dim3(128, B_), 256, 0, stream>>>(ws, out);
}